// Round 1
// baseline (393.921 us; speedup 1.0000x reference)
//
#include <hip/hip_runtime.h>

// BrickVectorEdgeModel on MI355X (gfx950).
// Plan: prep (fp32->bf16 weights) -> node_kernel (768-row MLP, u/v fp32)
//       -> edge_kernel (fused 96-edge chain: build E0 in LDS, two 512x512
//          bf16 MFMA layers in-place in LDS, W_out projection + reduce).

typedef short  short8  __attribute__((ext_vector_type(8)));
typedef short  short4v __attribute__((ext_vector_type(4)));
typedef float  f32x4   __attribute__((ext_vector_type(4)));

#define LDSW 520   // LDS row stride in bf16 elems (512 + 8 pad -> 1040B, 16B-aligned)

__device__ inline unsigned short f2bf(float x) {
  unsigned u = __float_as_uint(x);
  unsigned r = (u + 0x7FFFu + ((u >> 16) & 1u)) >> 16;  // RNE
  return (unsigned short)r;
}

template <int MT>
__device__ inline void zero_acc(f32x4 (&acc)[MT][4]) {
#pragma unroll
  for (int mt = 0; mt < MT; ++mt)
#pragma unroll
    for (int nt = 0; nt < 4; ++nt) {
      f32x4 z = {0.f, 0.f, 0.f, 0.f};
      acc[mt][nt] = z;
    }
}

// C = A(LDS, MT*16 x 512 bf16) @ W^T (global bf16 [512][512], row-major n-major)
// wave covers 64 n-cols (wave*64), MT m-tiles of 16. 1-step register double buffer.
template <int MT>
__device__ inline void gemm_kloop(const short* A, const short* __restrict__ W,
                                  int lane, int wave, f32x4 (&acc)[MT][4]) {
  const int mrow = lane & 15, kg = lane >> 4, nbase = wave * 64;
  const short* Al = A + mrow * LDSW + kg * 8;
  const short* Wl = W + (nbase + mrow) * 512 + kg * 8;
  short8 aF[2][MT], bF[2][4];
#pragma unroll
  for (int mt = 0; mt < MT; ++mt) aF[0][mt] = *(const short8*)(Al + mt * 16 * LDSW);
#pragma unroll
  for (int nt = 0; nt < 4; ++nt) bF[0][nt] = *(const short8*)(Wl + nt * 16 * 512);
  for (int ks = 0; ks < 16; ++ks) {
    const int cur = ks & 1, nxt = cur ^ 1;
    const int k1 = ((ks + 1) & 15) * 32;
#pragma unroll
    for (int mt = 0; mt < MT; ++mt)
      aF[nxt][mt] = *(const short8*)(Al + mt * 16 * LDSW + k1);
#pragma unroll
    for (int nt = 0; nt < 4; ++nt)
      bF[nxt][nt] = *(const short8*)(Wl + nt * 16 * 512 + k1);
#pragma unroll
    for (int mt = 0; mt < MT; ++mt)
#pragma unroll
      for (int nt = 0; nt < 4; ++nt)
        acc[mt][nt] = __builtin_amdgcn_mfma_f32_16x16x32_bf16(
            aF[cur][mt], bF[cur][nt], acc[mt][nt], 0, 0, 0);
  }
}

// relu(acc + bias[col]) -> bf16 -> LDS (in-place layer chaining)
__device__ inline void store_relu_lds(short* A, const float* __restrict__ bias,
                                      int lane, int wave, f32x4 (&acc)[6][4]) {
  const int mrow = lane & 15, kg = lane >> 4, nbase = wave * 64;
  float bs[4];
#pragma unroll
  for (int nt = 0; nt < 4; ++nt) bs[nt] = bias[nbase + nt * 16 + mrow];
#pragma unroll
  for (int mt = 0; mt < 6; ++mt)
#pragma unroll
    for (int nt = 0; nt < 4; ++nt)
#pragma unroll
      for (int r = 0; r < 4; ++r) {
        const int row = mt * 16 + kg * 4 + r;       // C layout: row=(lane>>4)*4+reg
        const int col = nbase + nt * 16 + mrow;     //           col=lane&15
        const float x = fmaxf(acc[mt][nt][r] + bs[nt], 0.f);
        A[row * LDSW + col] = (short)f2bf(x);
      }
}

// ---------------- prep: convert weights to bf16 in workspace ----------------
__global__ void prep_kernel(const float* __restrict__ Wa, const float* __restrict__ Wb,
                            const float* __restrict__ Wca, const float* __restrict__ Wcb,
                            const float* __restrict__ Wcc, const float* __restrict__ Wout,
                            short* __restrict__ outS) {
  const int tid = blockIdx.x * blockDim.x + threadIdx.x;
  const int stride = gridDim.x * blockDim.x;
  const int M = 262144;
  for (int i = tid; i < 6 * M + 1024; i += stride) {
    float x;
    if (i < M) x = Wa[i];
    else if (i < 2 * M) x = Wb[i - M];
    else if (i < 3 * M) { const int t = i - 2 * M; x = Wca[(t >> 9) * 1024 + (t & 511)]; }
    else if (i < 4 * M) { const int t = i - 3 * M; x = Wca[(t >> 9) * 1024 + 512 + (t & 511)]; }
    else if (i < 5 * M) x = Wcb[i - 4 * M];
    else if (i < 6 * M) x = Wcc[i - 5 * M];
    else x = Wout[i - 6 * M];
    outS[i] = (short)f2bf(x);
  }
}

// ---------------- node stage: f1 -> f2 -> u,v (24 WGs x 32 nodes) ----------------
__global__ __launch_bounds__(512, 2) void node_kernel(
    const float* __restrict__ bv, const float* __restrict__ xy,
    const float* __restrict__ Wxy, const float* __restrict__ bxy,
    const float* __restrict__ ba, const float* __restrict__ bb,
    const short* __restrict__ Wa, const short* __restrict__ Wb,
    const short* __restrict__ W1, const short* __restrict__ W2,
    float* __restrict__ u, float* __restrict__ v) {
  __shared__ short A[32 * LDSW];
  __shared__ float xyl[64];
  const int tid = threadIdx.x, lane = tid & 63, wave = tid >> 6;
  const int node0 = blockIdx.x * 32;

  {  // stage bv tile -> bf16 LDS
    const int hc = (tid & 127) * 4, m0 = tid >> 7;
    for (int m = m0; m < 32; m += 4) {
      const float4 t = *(const float4*)(bv + (node0 + m) * 512 + hc);
      short4v s;
      s.x = (short)f2bf(t.x); s.y = (short)f2bf(t.y);
      s.z = (short)f2bf(t.z); s.w = (short)f2bf(t.w);
      *(short4v*)&A[m * LDSW + hc] = s;
    }
    if (tid < 64) xyl[tid] = xy[node0 * 2 + tid];
  }
  __syncthreads();

  const int mrow = lane & 15, kg = lane >> 4, nbase = wave * 64;
  f32x4 acc[2][4];

  // layer 1: relu(bv@Wa^T + xy@Wxy^T + ba + bxy)
  zero_acc<2>(acc);
  gemm_kloop<2>(A, Wa, lane, wave, acc);
  __syncthreads();
  {
    float bs[4], w0[4], w1[4];
#pragma unroll
    for (int nt = 0; nt < 4; ++nt) {
      const int col = nbase + nt * 16 + mrow;
      bs[nt] = ba[col] + bxy[col];
      w0[nt] = Wxy[col * 2 + 0];
      w1[nt] = Wxy[col * 2 + 1];
    }
#pragma unroll
    for (int mt = 0; mt < 2; ++mt)
#pragma unroll
      for (int nt = 0; nt < 4; ++nt)
#pragma unroll
        for (int r = 0; r < 4; ++r) {
          const int row = mt * 16 + kg * 4 + r;
          const int col = nbase + nt * 16 + mrow;
          float x = acc[mt][nt][r] + bs[nt] + xyl[row * 2] * w0[nt] + xyl[row * 2 + 1] * w1[nt];
          A[row * LDSW + col] = (short)f2bf(fmaxf(x, 0.f));
        }
  }
  __syncthreads();

  // layer 2: relu(f1@Wb^T + bb)
  zero_acc<2>(acc);
  gemm_kloop<2>(A, Wb, lane, wave, acc);
  __syncthreads();
  {
    float bs[4];
#pragma unroll
    for (int nt = 0; nt < 4; ++nt) bs[nt] = bb[nbase + nt * 16 + mrow];
#pragma unroll
    for (int mt = 0; mt < 2; ++mt)
#pragma unroll
      for (int nt = 0; nt < 4; ++nt)
#pragma unroll
        for (int r = 0; r < 4; ++r) {
          const int row = mt * 16 + kg * 4 + r;
          const int col = nbase + nt * 16 + mrow;
          A[row * LDSW + col] = (short)f2bf(fmaxf(acc[mt][nt][r] + bs[nt], 0.f));
        }
  }
  __syncthreads();

  // u = f2@W1^T (fp32, no bias/relu)
  zero_acc<2>(acc);
  gemm_kloop<2>(A, W1, lane, wave, acc);
#pragma unroll
  for (int mt = 0; mt < 2; ++mt)
#pragma unroll
    for (int nt = 0; nt < 4; ++nt)
#pragma unroll
      for (int r = 0; r < 4; ++r) {
        const int row = mt * 16 + kg * 4 + r;
        const int col = nbase + nt * 16 + mrow;
        u[(node0 + row) * 512 + col] = acc[mt][nt][r];
      }
  // v = f2@W2^T
  zero_acc<2>(acc);
  gemm_kloop<2>(A, W2, lane, wave, acc);
#pragma unroll
  for (int mt = 0; mt < 2; ++mt)
#pragma unroll
    for (int nt = 0; nt < 4; ++nt)
#pragma unroll
      for (int r = 0; r < 4; ++r) {
        const int row = mt * 16 + kg * 4 + r;
        const int col = nbase + nt * 16 + mrow;
        v[(node0 + row) * 512 + col] = acc[mt][nt][r];
      }
}

// ---------------- edge stage: fused E0 -> E1 -> E2 -> out ----------------
__global__ __launch_bounds__(512, 2) void edge_kernel(
    const float* __restrict__ u, const float* __restrict__ v,
    const short* __restrict__ Wcb, const short* __restrict__ Wcc,
    const short* __restrict__ Wout,
    const float* __restrict__ bca, const float* __restrict__ bcb,
    const float* __restrict__ bcc, const float* __restrict__ bout,
    float* __restrict__ out) {
  __shared__ short A[96 * LDSW];       // 99840 B
  __shared__ float red[96 * 2 * 8];    //  6144 B
  const int tid = threadIdx.x, lane = tid & 63, wave = tid >> 6;
  const int blk = blockIdx.x;
  const int b = blk / 384, rem = blk % 384, i = rem >> 1, jt = rem & 1;
  const float* urow0 = u + (b * 192 + jt * 96) * 512;  // e0 row m uses u[b, jt*96+m]
  const float* vrow  = v + (b * 192 + i) * 512;

  {  // Phase 0: E0 = relu(u[j] + v[i] + b_ca) -> bf16 LDS
    const int hc = (tid & 127) * 4, m0 = tid >> 7;
    const float4 vv = *(const float4*)(vrow + hc);
    const float4 bb = *(const float4*)(bca + hc);
    for (int m = m0; m < 96; m += 4) {
      const float4 uu = *(const float4*)(urow0 + m * 512 + hc);
      short4v s;
      s.x = (short)f2bf(fmaxf(uu.x + vv.x + bb.x, 0.f));
      s.y = (short)f2bf(fmaxf(uu.y + vv.y + bb.y, 0.f));
      s.z = (short)f2bf(fmaxf(uu.z + vv.z + bb.z, 0.f));
      s.w = (short)f2bf(fmaxf(uu.w + vv.w + bb.w, 0.f));
      *(short4v*)&A[m * LDSW + hc] = s;
    }
  }
  __syncthreads();

  f32x4 acc[6][4];

  // layer cb
  zero_acc<6>(acc);
  gemm_kloop<6>(A, Wcb, lane, wave, acc);
  __syncthreads();                 // all waves done reading E0
  store_relu_lds(A, bcb, lane, wave, acc);
  __syncthreads();

  // layer cc
  zero_acc<6>(acc);
  gemm_kloop<6>(A, Wcc, lane, wave, acc);
  __syncthreads();
  store_relu_lds(A, bcc, lane, wave, acc);
  __syncthreads();

  // final: out = E2 @ Wout^T + bout.  k-split across 8 waves, n padded 2->16.
  f32x4 oacc[6];
#pragma unroll
  for (int mt = 0; mt < 6; ++mt) { f32x4 z = {0.f, 0.f, 0.f, 0.f}; oacc[mt] = z; }
  const int n = lane & 15, kg = lane >> 4;
#pragma unroll
  for (int kk = 0; kk < 2; ++kk) {
    const int k0 = wave * 64 + kk * 32 + kg * 8;
    short8 bf = {0, 0, 0, 0, 0, 0, 0, 0};
    if (n < 2) bf = *(const short8*)(Wout + n * 512 + k0);
#pragma unroll
    for (int mt = 0; mt < 6; ++mt) {
      const short8 af = *(const short8*)(A + (mt * 16 + n) * LDSW + k0);
      oacc[mt] = __builtin_amdgcn_mfma_f32_16x16x32_bf16(af, bf, oacc[mt], 0, 0, 0);
    }
  }
  if (n < 2) {
#pragma unroll
    for (int mt = 0; mt < 6; ++mt)
#pragma unroll
      for (int r = 0; r < 4; ++r) {
        const int row = mt * 16 + kg * 4 + r;
        red[(row * 2 + n) * 8 + wave] = oacc[mt][r];
      }
  }
  __syncthreads();
  if (tid < 192) {
    const int row = tid >> 1, o = tid & 1;
    float s = bout[o];
#pragma unroll
    for (int w = 0; w < 8; ++w) s += red[(row * 2 + o) * 8 + w];
    out[((b * 192 + i) * 192 + jt * 96 + row) * 2 + o] = s;
  }
}

extern "C" void kernel_launch(void* const* d_in, const int* in_sizes, int n_in,
                              void* d_out, int out_size, void* d_ws, size_t ws_size,
                              hipStream_t stream) {
  const float* bv   = (const float*)d_in[0];
  const float* xy   = (const float*)d_in[1];
  const float* Wxy  = (const float*)d_in[2];
  const float* bxy  = (const float*)d_in[3];
  const float* Wa   = (const float*)d_in[4];
  const float* ba   = (const float*)d_in[5];
  const float* Wb   = (const float*)d_in[6];
  const float* bb   = (const float*)d_in[7];
  const float* Wca  = (const float*)d_in[8];
  const float* bca  = (const float*)d_in[9];
  const float* Wcb  = (const float*)d_in[10];
  const float* bcb  = (const float*)d_in[11];
  const float* Wcc  = (const float*)d_in[12];
  const float* bcc  = (const float*)d_in[13];
  const float* Wout = (const float*)d_in[14];
  const float* bout = (const float*)d_in[15];
  float* out = (float*)d_out;

  // ws layout: bf16 weights [0, ~3MB), u fp32 @ 4MB, v fp32 @ 4MB+1.5MB
  short* S = (short*)d_ws;
  short* WaB   = S;
  short* WbB   = S + 262144;
  short* W1B   = S + 524288;
  short* W2B   = S + 786432;
  short* WcbB  = S + 1048576;
  short* WccB  = S + 1310720;
  short* WoutB = S + 1572864;
  float* u = (float*)((char*)d_ws + (4u << 20));
  float* v = u + 393216;

  prep_kernel<<<512, 256, 0, stream>>>(Wa, Wb, Wca, Wcb, Wcc, Wout, S);
  node_kernel<<<24, 512, 0, stream>>>(bv, xy, Wxy, bxy, ba, bb, WaB, WbB, W1B, W2B, u, v);
  edge_kernel<<<1536, 512, 0, stream>>>(u, v, WcbB, WccB, WoutB, bca, bcb, bcc, bout, out);
}

// Round 2
// 371.246 us; speedup vs baseline: 1.0611x; 1.0611x over previous
//
#include <hip/hip_runtime.h>

// BrickVectorEdgeModel on MI355X (gfx950).
// R2: full k-loop unroll (static double-buffer regs), swapped MFMA operands
// (W as A-operand, E as B-operand) so epilogue stores are ds_write_b64 /
// float4 instead of scalar u16; node stage 48 blocks.

typedef short  short8  __attribute__((ext_vector_type(8)));
typedef short  short4v __attribute__((ext_vector_type(4)));
typedef float  f32x4   __attribute__((ext_vector_type(4)));

#define LDSW 520   // LDS row stride in bf16 elems (520*2B = 1040B, 16B-aligned)

__device__ inline unsigned short f2bf(float x) {
  unsigned u = __float_as_uint(x);
  unsigned r = (u + 0x7FFFu + ((u >> 16) & 1u)) >> 16;  // RNE
  return (unsigned short)r;
}

template <int MT, int NT>
__device__ inline void zero_acc(f32x4 (&acc)[MT][NT]) {
#pragma unroll
  for (int mt = 0; mt < MT; ++mt)
#pragma unroll
    for (int nt = 0; nt < NT; ++nt) {
      f32x4 z = {0.f, 0.f, 0.f, 0.f};
      acc[mt][nt] = z;
    }
}

// acc[mt][nt] (+)= W-tile x E-tile.  W passed as MFMA A-operand (m = out-col),
// E as B-operand (n = edge-row).  D[m=outcol][n=row]: lane holds 4 consecutive
// out-cols (kg*4+r) at edge-row (mt*16 + (lane&15)).
// E: LDS bf16 [MT*16][512] stride LDSW.  W: global bf16 [512][512] row-major.
template <int MT, int NT>
__device__ inline void gemm_kloop(const short* E, const short* __restrict__ W,
                                  int lane, int nbase, f32x4 (&acc)[MT][NT]) {
  const int mrow = lane & 15, kg = lane >> 4;
  const short* El = E + mrow * LDSW + kg * 8;
  const short* Wl = W + (nbase + mrow) * 512 + kg * 8;
  short8 eF[2][MT], wF[2][NT];
#pragma unroll
  for (int mt = 0; mt < MT; ++mt) eF[0][mt] = *(const short8*)(El + mt * 16 * LDSW);
#pragma unroll
  for (int nt = 0; nt < NT; ++nt) wF[0][nt] = *(const short8*)(Wl + nt * 16 * 512);
#pragma unroll
  for (int ks = 0; ks < 16; ++ks) {
    const int cur = ks & 1, nxt = cur ^ 1;
    if (ks < 15) {
      const int k1 = (ks + 1) * 32;
#pragma unroll
      for (int mt = 0; mt < MT; ++mt)
        eF[nxt][mt] = *(const short8*)(El + mt * 16 * LDSW + k1);
#pragma unroll
      for (int nt = 0; nt < NT; ++nt)
        wF[nxt][nt] = *(const short8*)(Wl + nt * 16 * 512 + k1);
    }
#pragma unroll
    for (int mt = 0; mt < MT; ++mt)
#pragma unroll
      for (int nt = 0; nt < NT; ++nt)
        acc[mt][nt] = __builtin_amdgcn_mfma_f32_16x16x32_bf16(
            wF[cur][nt], eF[cur][mt], acc[mt][nt], 0, 0, 0);
  }
}

// relu(acc + bias[outcol]) -> bf16 -> LDS, 8B vector writes.
template <int MT, int NT>
__device__ inline void store_relu_lds(short* E, const float* __restrict__ bias,
                                      int lane, int nbase, f32x4 (&acc)[MT][NT]) {
  const int mrow = lane & 15, kg = lane >> 4;
#pragma unroll
  for (int nt = 0; nt < NT; ++nt) {
    const int oc = nbase + nt * 16 + kg * 4;
    const float4 bs = *(const float4*)(bias + oc);
#pragma unroll
    for (int mt = 0; mt < MT; ++mt) {
      short4v s;
      s.x = (short)f2bf(fmaxf(acc[mt][nt][0] + bs.x, 0.f));
      s.y = (short)f2bf(fmaxf(acc[mt][nt][1] + bs.y, 0.f));
      s.z = (short)f2bf(fmaxf(acc[mt][nt][2] + bs.z, 0.f));
      s.w = (short)f2bf(fmaxf(acc[mt][nt][3] + bs.w, 0.f));
      *(short4v*)&E[(mt * 16 + mrow) * LDSW + oc] = s;
    }
  }
}

// ---------------- prep: convert weights to bf16 in workspace ----------------
__global__ void prep_kernel(const float* __restrict__ Wa, const float* __restrict__ Wb,
                            const float* __restrict__ Wca, const float* __restrict__ Wcb,
                            const float* __restrict__ Wcc, const float* __restrict__ Wout,
                            short* __restrict__ outS) {
  const int tid = blockIdx.x * blockDim.x + threadIdx.x;
  const int stride = gridDim.x * blockDim.x;
  const int M = 262144;
  for (int i = tid; i < 6 * M + 1024; i += stride) {
    float x;
    if (i < M) x = Wa[i];
    else if (i < 2 * M) x = Wb[i - M];
    else if (i < 3 * M) { const int t = i - 2 * M; x = Wca[(t >> 9) * 1024 + (t & 511)]; }
    else if (i < 4 * M) { const int t = i - 3 * M; x = Wca[(t >> 9) * 1024 + 512 + (t & 511)]; }
    else if (i < 5 * M) x = Wcb[i - 4 * M];
    else if (i < 6 * M) x = Wcc[i - 5 * M];
    else x = Wout[i - 6 * M];
    outS[i] = (short)f2bf(x);
  }
}

// ---------------- node stage: f1 -> f2 -> u,v (48 WGs x 16 nodes) ----------------
__global__ __launch_bounds__(512, 2) void node_kernel(
    const float* __restrict__ bv, const float* __restrict__ xy,
    const float* __restrict__ Wxy, const float* __restrict__ bxy,
    const float* __restrict__ ba, const float* __restrict__ bb,
    const short* __restrict__ Wa, const short* __restrict__ Wb,
    const short* __restrict__ W1, const short* __restrict__ W2,
    float* __restrict__ u, float* __restrict__ v) {
  __shared__ short A[16 * LDSW];
  __shared__ float xyl[32];
  const int tid = threadIdx.x, lane = tid & 63, wave = tid >> 6;
  const int node0 = blockIdx.x * 16;

  {  // stage bv tile -> bf16 LDS
    const int hc = (tid & 127) * 4, m0 = tid >> 7;
#pragma unroll
    for (int m = m0; m < 16; m += 4) {
      const float4 t = *(const float4*)(bv + (node0 + m) * 512 + hc);
      short4v s;
      s.x = (short)f2bf(t.x); s.y = (short)f2bf(t.y);
      s.z = (short)f2bf(t.z); s.w = (short)f2bf(t.w);
      *(short4v*)&A[m * LDSW + hc] = s;
    }
    if (tid < 32) xyl[tid] = xy[node0 * 2 + tid];
  }
  __syncthreads();

  const int mrow = lane & 15, kg = lane >> 4, nbase = wave * 64;
  f32x4 acc[1][4];

  // layer 1: relu(bv@Wa^T + xy@Wxy^T + ba + bxy)
  zero_acc<1, 4>(acc);
  gemm_kloop<1, 4>(A, Wa, lane, nbase, acc);
  __syncthreads();
  {
    const float x0 = xyl[mrow * 2], x1 = xyl[mrow * 2 + 1];
#pragma unroll
    for (int nt = 0; nt < 4; ++nt) {
      const int oc = nbase + nt * 16 + kg * 4;
      const float4 b1 = *(const float4*)(ba + oc);
      const float4 b2 = *(const float4*)(bxy + oc);
      short4v s;
#pragma unroll
      for (int r = 0; r < 4; ++r) {
        const float w0 = Wxy[(oc + r) * 2], w1 = Wxy[(oc + r) * 2 + 1];
        const float bsr = (r == 0 ? b1.x + b2.x : r == 1 ? b1.y + b2.y
                          : r == 2 ? b1.z + b2.z : b1.w + b2.w);
        const float xv = fmaxf(acc[0][nt][r] + bsr + x0 * w0 + x1 * w1, 0.f);
        ((short*)&s)[r] = (short)f2bf(xv);
      }
      *(short4v*)&A[mrow * LDSW + oc] = s;
    }
  }
  __syncthreads();

  // layer 2: relu(f1@Wb^T + bb)
  zero_acc<1, 4>(acc);
  gemm_kloop<1, 4>(A, Wb, lane, nbase, acc);
  __syncthreads();
  store_relu_lds<1, 4>(A, bb, lane, nbase, acc);
  __syncthreads();

  // u = f2@W1^T (fp32), v = f2@W2^T
  zero_acc<1, 4>(acc);
  gemm_kloop<1, 4>(A, W1, lane, nbase, acc);
#pragma unroll
  for (int nt = 0; nt < 4; ++nt) {
    const int oc = nbase + nt * 16 + kg * 4;
    *(f32x4*)&u[(node0 + mrow) * 512 + oc] = acc[0][nt];
  }
  zero_acc<1, 4>(acc);
  gemm_kloop<1, 4>(A, W2, lane, nbase, acc);
#pragma unroll
  for (int nt = 0; nt < 4; ++nt) {
    const int oc = nbase + nt * 16 + kg * 4;
    *(f32x4*)&v[(node0 + mrow) * 512 + oc] = acc[0][nt];
  }
}

// ---------------- edge stage: fused E0 -> E1 -> E2 -> out ----------------
__global__ __launch_bounds__(512, 2) void edge_kernel(
    const float* __restrict__ u, const float* __restrict__ v,
    const short* __restrict__ Wcb, const short* __restrict__ Wcc,
    const short* __restrict__ Wout,
    const float* __restrict__ bca, const float* __restrict__ bcb,
    const float* __restrict__ bcc, const float* __restrict__ bout,
    float* __restrict__ out) {
  __shared__ short A[96 * LDSW];       // 99840 B
  __shared__ float red[96 * 2 * 8];    //  6144 B
  const int tid = threadIdx.x, lane = tid & 63, wave = tid >> 6;
  const int blk = blockIdx.x;
  const int b = blk / 384, rem = blk % 384, i = rem >> 1, jt = rem & 1;
  const float* urow0 = u + (b * 192 + jt * 96) * 512;  // e0 row m uses u[b, jt*96+m]
  const float* vrow  = v + (b * 192 + i) * 512;

  {  // Phase 0: E0 = relu(u[j] + v[i] + b_ca) -> bf16 LDS
    const int hc = (tid & 127) * 4, m0 = tid >> 7;
    const float4 vv = *(const float4*)(vrow + hc);
    const float4 bb = *(const float4*)(bca + hc);
#pragma unroll 4
    for (int m = m0; m < 96; m += 4) {
      const float4 uu = *(const float4*)(urow0 + m * 512 + hc);
      short4v s;
      s.x = (short)f2bf(fmaxf(uu.x + vv.x + bb.x, 0.f));
      s.y = (short)f2bf(fmaxf(uu.y + vv.y + bb.y, 0.f));
      s.z = (short)f2bf(fmaxf(uu.z + vv.z + bb.z, 0.f));
      s.w = (short)f2bf(fmaxf(uu.w + vv.w + bb.w, 0.f));
      *(short4v*)&A[m * LDSW + hc] = s;
    }
  }
  __syncthreads();

  const int nbase = wave * 64;
  f32x4 acc[6][4];

  // layer cb
  zero_acc<6, 4>(acc);
  gemm_kloop<6, 4>(A, Wcb, lane, nbase, acc);
  __syncthreads();                 // all waves done reading E0
  store_relu_lds<6, 4>(A, bcb, lane, nbase, acc);
  __syncthreads();

  // layer cc
  zero_acc<6, 4>(acc);
  gemm_kloop<6, 4>(A, Wcc, lane, nbase, acc);
  __syncthreads();
  store_relu_lds<6, 4>(A, bcc, lane, nbase, acc);
  __syncthreads();

  // final: out = E2 @ Wout^T + bout.  k-split across 8 waves, n padded 2->16.
  f32x4 oacc[6];
#pragma unroll
  for (int mt = 0; mt < 6; ++mt) { f32x4 z = {0.f, 0.f, 0.f, 0.f}; oacc[mt] = z; }
  const int n = lane & 15, kg2 = lane >> 4;
#pragma unroll
  for (int kk = 0; kk < 2; ++kk) {
    const int k0 = wave * 64 + kk * 32 + kg2 * 8;
    short8 bf = {0, 0, 0, 0, 0, 0, 0, 0};
    if (n < 2) bf = *(const short8*)(Wout + n * 512 + k0);
#pragma unroll
    for (int mt = 0; mt < 6; ++mt) {
      const short8 af = *(const short8*)(A + (mt * 16 + n) * LDSW + k0);
      oacc[mt] = __builtin_amdgcn_mfma_f32_16x16x32_bf16(af, bf, oacc[mt], 0, 0, 0);
    }
  }
  if (n < 2) {
#pragma unroll
    for (int mt = 0; mt < 6; ++mt)
#pragma unroll
      for (int r = 0; r < 4; ++r) {
        const int row = mt * 16 + kg2 * 4 + r;
        red[(row * 2 + n) * 8 + wave] = oacc[mt][r];
      }
  }
  __syncthreads();
  if (tid < 192) {
    const int row = tid >> 1, o = tid & 1;
    float s = bout[o];
#pragma unroll
    for (int w = 0; w < 8; ++w) s += red[(row * 2 + o) * 8 + w];
    out[((b * 192 + i) * 192 + jt * 96 + row) * 2 + o] = s;
  }
}

extern "C" void kernel_launch(void* const* d_in, const int* in_sizes, int n_in,
                              void* d_out, int out_size, void* d_ws, size_t ws_size,
                              hipStream_t stream) {
  const float* bv   = (const float*)d_in[0];
  const float* xy   = (const float*)d_in[1];
  const float* Wxy  = (const float*)d_in[2];
  const float* bxy  = (const float*)d_in[3];
  const float* Wa   = (const float*)d_in[4];
  const float* ba   = (const float*)d_in[5];
  const float* Wb   = (const float*)d_in[6];
  const float* bb   = (const float*)d_in[7];
  const float* Wca  = (const float*)d_in[8];
  const float* bca  = (const float*)d_in[9];
  const float* Wcb  = (const float*)d_in[10];
  const float* bcb  = (const float*)d_in[11];
  const float* Wcc  = (const float*)d_in[12];
  const float* bcc  = (const float*)d_in[13];
  const float* Wout = (const float*)d_in[14];
  const float* bout = (const float*)d_in[15];
  float* out = (float*)d_out;

  // ws layout: bf16 weights [0, ~3MB), u fp32 @ 4MB, v fp32 @ 4MB+1.5MB
  short* S = (short*)d_ws;
  short* WaB   = S;
  short* WbB   = S + 262144;
  short* W1B   = S + 524288;
  short* W2B   = S + 786432;
  short* WcbB  = S + 1048576;
  short* WccB  = S + 1310720;
  short* WoutB = S + 1572864;
  float* u = (float*)((char*)d_ws + (4u << 20));
  float* v = u + 393216;

  prep_kernel<<<512, 256, 0, stream>>>(Wa, Wb, Wca, Wcb, Wcc, Wout, S);
  node_kernel<<<48, 512, 0, stream>>>(bv, xy, Wxy, bxy, ba, bb, WaB, WbB, W1B, W2B, u, v);
  edge_kernel<<<1536, 512, 0, stream>>>(u, v, WcbB, WccB, WoutB, bca, bcb, bcc, bout, out);
}